// Round 6
// baseline (361.255 us; speedup 1.0000x reference)
//
#include <hip/hip_runtime.h>

// EfConv forward, CSR-based, fp16 payloads, atomic-free permute, 5 launches:
//   K0 zero:      deg[:]=0
//   K1 fused:     hist blocks first (rank[e]=deg[dst[e]]++), then transform blocks
//                 (t = fp16(node_feat @ W^T)) -- independent, overlap on the machine
//   K2 scan1wg:   offsets = exclusive_scan(deg), ONE workgroup (1024 thr, chunked)
//   K3 permute:   pos = offsets[dst[e]] + rank[e]; srcs[pos]=src[e]; efs[pos]=fp16(ef[e])
//                 (plain scatter stores -> L2 write-combines; NT here was a 4-5x loss, R4)
//   K4 aggregate: per node n (one wave, lanes=o), 16-deep masked gather chains:
//                 out[n,k,o] = b[o] + sum_j efs[j,k] * t[srcs[j],o]   (fp32 accum)
//                 srcs/efs wave-uniform (scalar path); only fp16 t row is a gather;
//                 out (coalesced write-once stream) via NONTEMPORAL stores.

#define FEATS 64
#define EDGE_DIM 8

typedef _Float16 half8 __attribute__((ext_vector_type(8)));

// ---- K0: zero deg ----
__global__ void __launch_bounds__(256) zero_kernel(int* __restrict__ p, int n)
{
    int i = blockIdx.x * 256 + threadIdx.x;
    if (i < n) p[i] = 0;
}

// ---- K1: fused hist + transform (hist blocks first) ----
__global__ void __launch_bounds__(256) hist_transform_kernel(
    const int* __restrict__ dst, int* __restrict__ deg, int* __restrict__ rank,
    int n_edges, int nbH,
    const float* __restrict__ nf, const float* __restrict__ W,
    _Float16* __restrict__ t, int n_nodes)
{
    const int tid = threadIdx.x;

    if (blockIdx.x < (unsigned)nbH) {
        // ---------- histogram part: rank[e] = deg[dst[e]]++ ----------
        int i4 = (blockIdx.x * 256 + tid) * 4;
        if (i4 + 3 < n_edges) {
            int4 d = *(const int4*)(dst + i4);
            int4 r;
            r.x = atomicAdd(&deg[d.x], 1);
            r.y = atomicAdd(&deg[d.y], 1);
            r.z = atomicAdd(&deg[d.z], 1);
            r.w = atomicAdd(&deg[d.w], 1);
            *(int4*)(rank + i4) = r;                 // coalesced
        } else {
            for (int e = i4; e < n_edges; ++e)
                rank[e] = atomicAdd(&deg[dst[e]], 1);
        }
        return;
    }

    // ---------- transform part: t[n][o] = fp16(sum_i nf[n][i]*W[o][i]) ----------
    __shared__ float sWt[FEATS * 65];
    __shared__ float srow[4][FEATS];
    const int bt = blockIdx.x - nbH;

    #pragma unroll
    for (int base = 0; base < FEATS * FEATS; base += 256) {
        int idx = base + tid;
        int o = idx >> 6;
        int i = idx & 63;
        sWt[i * 65 + o] = W[idx];
    }

    const int r = tid >> 6;
    const int o = tid & 63;
    const int node = bt * 4 + r;
    if (node < n_nodes) srow[r][o] = nf[(long)node * FEATS + o];
    __syncthreads();

    if (node >= n_nodes) return;
    float sum = 0.f;
    #pragma unroll
    for (int i = 0; i < FEATS; i++)
        sum += srow[r][i] * sWt[i * 65 + o];
    t[(long)node * FEATS + o] = (_Float16)sum;   // single rounding, fp32 accumulate
}

// ---- K2: single-workgroup exclusive scan (replaces 3-kernel scan) ----
__global__ void __launch_bounds__(1024) scan1wg_kernel(
    const int* __restrict__ deg, int* __restrict__ offsets, int n, int n_edges)
{
    const int tid = threadIdx.x;
    const int T = 1024;
    const int C = (n + T - 1) / T;               // elems per thread
    const int base = tid * C;

    // per-thread serial sum of chunk
    int s = 0;
    for (int j = 0; j < C; ++j) {
        int idx = base + j;
        if (idx < n) s += deg[idx];
    }

    // block-wide exclusive scan of per-thread sums: wave shuffle + wave partials
    const int lane = tid & 63;
    const int wid = tid >> 6;                    // 16 waves
    int incl = s;
    #pragma unroll
    for (int off = 1; off < 64; off <<= 1) {
        int v = __shfl_up(incl, off, 64);
        if (lane >= off) incl += v;
    }
    __shared__ int wsum[16];
    __shared__ int woff[16];
    if (lane == 63) wsum[wid] = incl;
    __syncthreads();
    if (tid == 0) {
        int acc = 0;
        #pragma unroll
        for (int i = 0; i < 16; i++) { woff[i] = acc; acc += wsum[i]; }
    }
    __syncthreads();

    int run = woff[wid] + incl - s;              // exclusive prefix of this chunk
    for (int j = 0; j < C; ++j) {
        int idx = base + j;
        if (idx < n) { offsets[idx] = run; run += deg[idx]; }
    }
    if (tid == T - 1) offsets[n] = n_edges;
}

// ---- K3: atomic-free permute of edges + fp16 ef rows ----
__global__ void __launch_bounds__(256) permute_ef_kernel(
    const int* __restrict__ src, const int* __restrict__ dst,
    const int* __restrict__ rank, const int* __restrict__ offsets,
    const float* __restrict__ ef,
    int* __restrict__ srcs, half8* __restrict__ efs, int n_edges)
{
    int i4 = (blockIdx.x * 256 + threadIdx.x) * 4;
    if (i4 + 3 < n_edges) {
        int4 s = *(const int4*)(src + i4);
        int4 d = *(const int4*)(dst + i4);
        int4 r = *(const int4*)(rank + i4);
        const float4* q = (const float4*)(ef + (long)i4 * EDGE_DIM);
        // 4 independent offsets gathers in flight (L2-resident, 200KB array)
        int p0 = offsets[d.x] + r.x;
        int p1 = offsets[d.y] + r.y;
        int p2 = offsets[d.z] + r.z;
        int p3 = offsets[d.w] + r.w;
        #pragma unroll
        for (int u = 0; u < 4; u++) {
            float4 a = q[2 * u], c = q[2 * u + 1];
            half8 h;
            h[0] = (_Float16)a.x; h[1] = (_Float16)a.y;
            h[2] = (_Float16)a.z; h[3] = (_Float16)a.w;
            h[4] = (_Float16)c.x; h[5] = (_Float16)c.y;
            h[6] = (_Float16)c.z; h[7] = (_Float16)c.w;
            int p = (u == 0) ? p0 : (u == 1) ? p1 : (u == 2) ? p2 : p3;
            efs[p] = h;                          // plain store: L2 write-combines
        }
        srcs[p0] = s.x; srcs[p1] = s.y; srcs[p2] = s.z; srcs[p3] = s.w;
    } else {
        for (int e = i4; e < n_edges; ++e) {
            int p = offsets[dst[e]] + rank[e];
            srcs[p] = src[e];
            const float* q = ef + (long)e * EDGE_DIM;
            half8 h;
            #pragma unroll
            for (int k = 0; k < EDGE_DIM; k++) h[k] = (_Float16)q[k];
            efs[p] = h;
        }
    }
}

// ---- K4: per-node aggregation, 16-deep chains, scalar fp16 ef ----
#define CHUNK 16

__global__ void __launch_bounds__(256) aggregate_seq_kernel(
    const _Float16* __restrict__ t, const half8* __restrict__ efs,
    const int* __restrict__ srcs, const int* __restrict__ offsets,
    const float* __restrict__ b, float* __restrict__ out, int n_nodes)
{
    const int node = __builtin_amdgcn_readfirstlane(
        (int)((blockIdx.x * 256 + threadIdx.x) >> 6));
    const int o = threadIdx.x & 63;
    if (node >= n_nodes) return;

    const int beg = offsets[node];
    const int end = offsets[node + 1];
    float acc[EDGE_DIM];
    #pragma unroll
    for (int k = 0; k < EDGE_DIM; k++) acc[k] = 0.f;

    if (end > beg) {
        const int last = end - 1;      // >= beg >= 0, so clamped idx always valid
        for (int j = beg; j < end; j += CHUNK) {
            int sidx[CHUNK];
            #pragma unroll
            for (int u = 0; u < CHUNK; u++) {
                int jj = j + u;
                sidx[u] = srcs[jj <= last ? jj : last];   // uniform clamp (scalar)
            }
            float tv[CHUNK];
            #pragma unroll
            for (int u = 0; u < CHUNK; u++)               // CHUNK gathers in flight
                tv[u] = (float)t[(long)sidx[u] * FEATS + o];
            #pragma unroll
            for (int u = 0; u < CHUNK; u++) {
                int jj = j + u;
                int ej = jj <= last ? jj : last;
                float tvm = (jj <= last) ? tv[u] : 0.f;   // mask tail
                half8 row = efs[ej];                      // uniform 16B (scalar path)
                #pragma unroll
                for (int k = 0; k < EDGE_DIM; k++)
                    acc[k] += (float)row[k] * tvm;
            }
        }
    }

    const float bo = b[o];
    float* op = out + (long)node * (EDGE_DIM * FEATS) + o;
    // out IS coalesced/full-line: NT is correct here (write-once stream)
    #pragma unroll
    for (int k = 0; k < EDGE_DIM; k++)
        __builtin_nontemporal_store(acc[k] + bo, op + k * FEATS);
}

extern "C" void kernel_launch(void* const* d_in, const int* in_sizes, int n_in,
                              void* d_out, int out_size, void* d_ws, size_t ws_size,
                              hipStream_t stream) {
    const float* node_feat = (const float*)d_in[0];
    const float* edge_feat = (const float*)d_in[1];
    const float* W         = (const float*)d_in[2];
    const float* b         = (const float*)d_in[3];
    const int*   src       = (const int*)d_in[4];
    const int*   dst       = (const int*)d_in[5];
    float* out = (float*)d_out;

    const int n_nodes = in_sizes[0] / FEATS;
    const int n_edges = in_sizes[4];
    const int nb_nodes = (n_nodes + 255) / 256;
    const int nbH = (n_edges + 1023) / 1024;           // hist blocks, 4 edges/thread
    const int nbT = (n_nodes + 3) / 4;                 // transform blocks

    // workspace layout (4B units)
    int* w = (int*)d_ws;
    _Float16* t   = (_Float16*)w;                      // N*64 halves = N*32 ints
    int* deg      = w + (long)n_nodes * (FEATS / 2);   // N
    int* offsets  = deg + n_nodes;                     // N+1
    int* rank     = offsets + n_nodes + 1;             // E
    int* srcs     = rank + n_edges;                    // E
    uintptr_t ea  = ((uintptr_t)(srcs + n_edges) + 15) & ~(uintptr_t)15;
    half8* efs    = (half8*)ea;                        // E * 16B

    zero_kernel<<<nb_nodes, 256, 0, stream>>>(deg, n_nodes);
    hist_transform_kernel<<<nbH + nbT, 256, 0, stream>>>(
        dst, deg, rank, n_edges, nbH, node_feat, W, t, n_nodes);
    scan1wg_kernel<<<1, 1024, 0, stream>>>(deg, offsets, n_nodes, n_edges);
    permute_ef_kernel<<<nbH, 256, 0, stream>>>(src, dst, rank, offsets, edge_feat,
                                               srcs, efs, n_edges);

    const long total_ag = (long)n_nodes * 64;
    aggregate_seq_kernel<<<(int)((total_ag + 255) / 256), 256, 0, stream>>>(
        t, efs, srcs, offsets, b, out, n_nodes);
}

// Round 8
// 286.470 us; speedup vs baseline: 1.2611x; 1.2611x over previous
//
#include <hip/hip_runtime.h>

// EfConv forward, CSR-based, fp16 payloads, atomic-free permute, 7 launches:
//   K0 zero:      deg[:]=0
//   K1 fused:     hist blocks first (rank[e]=deg[dst[e]]++), then transform blocks
//                 (t = fp16(node_feat @ W^T)) -- independent, overlap on the machine
//   K2a/2b/2c:    offsets = exclusive_scan(deg)  (multi-block 3-kernel scan;
//                 R6 lesson: 1-WG chunked scan = 94us, serial uncoalesced on 1 CU)
//   K3 permute:   pos = offsets[dst[e]] + rank[e]; srcs[pos]=src[e]; efs[pos]=fp16(ef[e])
//                 plain scatter stores (NT scatter was 4-5x write amp, R4);
//                 NT *loads* (via ext_vector float4 -- clang rejects HIP_vector_type)
//                 for the once-read ef stream.
//   K4 aggregate: per node n (one wave, lanes=o), 16-deep masked gather chains:
//                 out[n,k,o] = b[o] + sum_j efs[j,k] * t[srcs[j],o]   (fp32 accum)
//                 srcs/efs wave-uniform (scalar path); only fp16 t row is a gather;
//                 out (coalesced write-once stream) via NONTEMPORAL stores.

#define FEATS 64
#define EDGE_DIM 8

typedef _Float16 half8 __attribute__((ext_vector_type(8)));
typedef float f32x4 __attribute__((ext_vector_type(4)));

// ---- K0: zero deg ----
__global__ void __launch_bounds__(256) zero_kernel(int* __restrict__ p, int n)
{
    int i = blockIdx.x * 256 + threadIdx.x;
    if (i < n) p[i] = 0;
}

// ---- K1: fused hist + transform (hist blocks first) ----
__global__ void __launch_bounds__(256) hist_transform_kernel(
    const int* __restrict__ dst, int* __restrict__ deg, int* __restrict__ rank,
    int n_edges, int nbH,
    const float* __restrict__ nf, const float* __restrict__ W,
    _Float16* __restrict__ t, int n_nodes)
{
    const int tid = threadIdx.x;

    if (blockIdx.x < (unsigned)nbH) {
        // ---------- histogram part: rank[e] = deg[dst[e]]++ ----------
        int i4 = (blockIdx.x * 256 + tid) * 4;
        if (i4 + 3 < n_edges) {
            int4 d = *(const int4*)(dst + i4);
            int4 r;
            r.x = atomicAdd(&deg[d.x], 1);
            r.y = atomicAdd(&deg[d.y], 1);
            r.z = atomicAdd(&deg[d.z], 1);
            r.w = atomicAdd(&deg[d.w], 1);
            *(int4*)(rank + i4) = r;                 // coalesced
        } else {
            for (int e = i4; e < n_edges; ++e)
                rank[e] = atomicAdd(&deg[dst[e]], 1);
        }
        return;
    }

    // ---------- transform part: t[n][o] = fp16(sum_i nf[n][i]*W[o][i]) ----------
    __shared__ float sWt[FEATS * 65];
    __shared__ float srow[4][FEATS];
    const int bt = blockIdx.x - nbH;

    #pragma unroll
    for (int base = 0; base < FEATS * FEATS; base += 256) {
        int idx = base + tid;
        int o = idx >> 6;
        int i = idx & 63;
        sWt[i * 65 + o] = W[idx];
    }

    const int r = tid >> 6;
    const int o = tid & 63;
    const int node = bt * 4 + r;
    if (node < n_nodes) srow[r][o] = nf[(long)node * FEATS + o];
    __syncthreads();

    if (node >= n_nodes) return;
    float sum = 0.f;
    #pragma unroll
    for (int i = 0; i < FEATS; i++)
        sum += srow[r][i] * sWt[i * 65 + o];
    t[(long)node * FEATS + o] = (_Float16)sum;   // single rounding, fp32 accumulate
}

// ---- K2a: per-block partial sums of deg ----
__global__ void __launch_bounds__(256) partials_kernel(
    const int* __restrict__ deg, int* __restrict__ partials, int n)
{
    __shared__ int s[256];
    int i = blockIdx.x * 256 + threadIdx.x;
    s[threadIdx.x] = (i < n) ? deg[i] : 0;
    __syncthreads();
    for (int off = 128; off > 0; off >>= 1) {
        if (threadIdx.x < off) s[threadIdx.x] += s[threadIdx.x + off];
        __syncthreads();
    }
    if (threadIdx.x == 0) partials[blockIdx.x] = s[0];
}

// ---- K2b: exclusive scan of partials (single block, nb <= 256) ----
__global__ void __launch_bounds__(256) scan_partials_kernel(
    const int* __restrict__ partials, int* __restrict__ pscan, int nb)
{
    __shared__ int s[256];
    int tid = threadIdx.x;
    s[tid] = (tid < nb) ? partials[tid] : 0;
    for (int off = 1; off < 256; off <<= 1) {
        __syncthreads();
        int x = (tid >= off) ? s[tid - off] : 0;
        __syncthreads();
        s[tid] += x;
    }
    __syncthreads();
    pscan[tid] = (tid == 0) ? 0 : s[tid - 1];
}

// ---- K2c: block-local exclusive scan + add partial offset ----
__global__ void __launch_bounds__(256) scan_addback_kernel(
    const int* __restrict__ deg, const int* __restrict__ pscan,
    int* __restrict__ offsets, int n, int n_edges)
{
    __shared__ int s[256];
    int tid = threadIdx.x;
    int i = blockIdx.x * 256 + tid;
    int v = (i < n) ? deg[i] : 0;
    s[tid] = v;
    for (int off = 1; off < 256; off <<= 1) {
        __syncthreads();
        int x = (tid >= off) ? s[tid - off] : 0;
        __syncthreads();
        s[tid] += x;
    }
    __syncthreads();
    if (i < n)
        offsets[i] = pscan[blockIdx.x] + s[tid] - v;   // inclusive - self = exclusive
    if (blockIdx.x == 0 && tid == 0) offsets[n] = n_edges;
}

// ---- K3: atomic-free permute of edges + fp16 ef rows ----
__global__ void __launch_bounds__(256) permute_ef_kernel(
    const int* __restrict__ src, const int* __restrict__ dst,
    const int* __restrict__ rank, const int* __restrict__ offsets,
    const float* __restrict__ ef,
    int* __restrict__ srcs, half8* __restrict__ efs, int n_edges)
{
    int i4 = (blockIdx.x * 256 + threadIdx.x) * 4;
    if (i4 + 3 < n_edges) {
        int4 s = *(const int4*)(src + i4);
        int4 d = *(const int4*)(dst + i4);
        int4 r = *(const int4*)(rank + i4);
        const f32x4* q = (const f32x4*)(ef + (long)i4 * EDGE_DIM);
        // 4 independent offsets gathers in flight (L2-resident, 200KB array)
        int p0 = offsets[d.x] + r.x;
        int p1 = offsets[d.y] + r.y;
        int p2 = offsets[d.z] + r.z;
        int p3 = offsets[d.w] + r.w;
        #pragma unroll
        for (int u = 0; u < 4; u++) {
            // ef read exactly once: NT load keeps L2 free for scatter write-combining
            f32x4 a = __builtin_nontemporal_load(q + 2 * u);
            f32x4 c = __builtin_nontemporal_load(q + 2 * u + 1);
            half8 h;
            h[0] = (_Float16)a.x; h[1] = (_Float16)a.y;
            h[2] = (_Float16)a.z; h[3] = (_Float16)a.w;
            h[4] = (_Float16)c.x; h[5] = (_Float16)c.y;
            h[6] = (_Float16)c.z; h[7] = (_Float16)c.w;
            int p = (u == 0) ? p0 : (u == 1) ? p1 : (u == 2) ? p2 : p3;
            efs[p] = h;                          // plain store: L2 write-combines
        }
        srcs[p0] = s.x; srcs[p1] = s.y; srcs[p2] = s.z; srcs[p3] = s.w;
    } else {
        for (int e = i4; e < n_edges; ++e) {
            int p = offsets[dst[e]] + rank[e];
            srcs[p] = src[e];
            const float* q = ef + (long)e * EDGE_DIM;
            half8 h;
            #pragma unroll
            for (int k = 0; k < EDGE_DIM; k++) h[k] = (_Float16)q[k];
            efs[p] = h;
        }
    }
}

// ---- K4: per-node aggregation, 16-deep chains, scalar fp16 ef ----
#define CHUNK 16

__global__ void __launch_bounds__(256) aggregate_seq_kernel(
    const _Float16* __restrict__ t, const half8* __restrict__ efs,
    const int* __restrict__ srcs, const int* __restrict__ offsets,
    const float* __restrict__ b, float* __restrict__ out, int n_nodes)
{
    const int node = __builtin_amdgcn_readfirstlane(
        (int)((blockIdx.x * 256 + threadIdx.x) >> 6));
    const int o = threadIdx.x & 63;
    if (node >= n_nodes) return;

    const int beg = offsets[node];
    const int end = offsets[node + 1];
    float acc[EDGE_DIM];
    #pragma unroll
    for (int k = 0; k < EDGE_DIM; k++) acc[k] = 0.f;

    if (end > beg) {
        const int last = end - 1;      // >= beg >= 0, so clamped idx always valid
        for (int j = beg; j < end; j += CHUNK) {
            int sidx[CHUNK];
            #pragma unroll
            for (int u = 0; u < CHUNK; u++) {
                int jj = j + u;
                sidx[u] = srcs[jj <= last ? jj : last];   // uniform clamp (scalar)
            }
            float tv[CHUNK];
            #pragma unroll
            for (int u = 0; u < CHUNK; u++)               // CHUNK gathers in flight
                tv[u] = (float)t[(long)sidx[u] * FEATS + o];
            #pragma unroll
            for (int u = 0; u < CHUNK; u++) {
                int jj = j + u;
                int ej = jj <= last ? jj : last;
                float tvm = (jj <= last) ? tv[u] : 0.f;   // mask tail
                half8 row = efs[ej];                      // uniform 16B (scalar path)
                #pragma unroll
                for (int k = 0; k < EDGE_DIM; k++)
                    acc[k] += (float)row[k] * tvm;
            }
        }
    }

    const float bo = b[o];
    float* op = out + (long)node * (EDGE_DIM * FEATS) + o;
    // out IS coalesced/full-line: NT is correct here (write-once stream)
    #pragma unroll
    for (int k = 0; k < EDGE_DIM; k++)
        __builtin_nontemporal_store(acc[k] + bo, op + k * FEATS);
}

extern "C" void kernel_launch(void* const* d_in, const int* in_sizes, int n_in,
                              void* d_out, int out_size, void* d_ws, size_t ws_size,
                              hipStream_t stream) {
    const float* node_feat = (const float*)d_in[0];
    const float* edge_feat = (const float*)d_in[1];
    const float* W         = (const float*)d_in[2];
    const float* b         = (const float*)d_in[3];
    const int*   src       = (const int*)d_in[4];
    const int*   dst       = (const int*)d_in[5];
    float* out = (float*)d_out;

    const int n_nodes = in_sizes[0] / FEATS;
    const int n_edges = in_sizes[4];
    const int nb_nodes = (n_nodes + 255) / 256;
    const int nbH = (n_edges + 1023) / 1024;           // hist/permute blocks, 4 edges/thread
    const int nbT = (n_nodes + 3) / 4;                 // transform blocks

    // workspace layout (4B units)
    int* w = (int*)d_ws;
    _Float16* t   = (_Float16*)w;                      // N*64 halves = N*32 ints
    int* deg      = w + (long)n_nodes * (FEATS / 2);   // N
    int* offsets  = deg + n_nodes;                     // N+1
    int* partials = offsets + n_nodes + 1;             // 256
    int* pscan    = partials + 256;                    // 256
    int* rank     = pscan + 256;                       // E
    int* srcs     = rank + n_edges;                    // E
    uintptr_t ea  = ((uintptr_t)(srcs + n_edges) + 15) & ~(uintptr_t)15;
    half8* efs    = (half8*)ea;                        // E * 16B

    zero_kernel<<<nb_nodes, 256, 0, stream>>>(deg, n_nodes);
    hist_transform_kernel<<<nbH + nbT, 256, 0, stream>>>(
        dst, deg, rank, n_edges, nbH, node_feat, W, t, n_nodes);
    partials_kernel<<<nb_nodes, 256, 0, stream>>>(deg, partials, n_nodes);
    scan_partials_kernel<<<1, 256, 0, stream>>>(partials, pscan, nb_nodes);
    scan_addback_kernel<<<nb_nodes, 256, 0, stream>>>(deg, pscan, offsets,
                                                      n_nodes, n_edges);
    permute_ef_kernel<<<nbH, 256, 0, stream>>>(src, dst, rank, offsets, edge_feat,
                                               srcs, efs, n_edges);

    const long total_ag = (long)n_nodes * 64;
    aggregate_seq_kernel<<<(int)((total_ag + 255) / 256), 256, 0, stream>>>(
        t, efs, srcs, offsets, b, out, n_nodes);
}

// Round 9
// 276.088 us; speedup vs baseline: 1.3085x; 1.0376x over previous
//
#include <hip/hip_runtime.h>

// EfConv forward, CSR-based, fp16 payloads, atomic-free permute:
//   K0 zero:      deg[:]=0
//   K1 fused, 3 block ranges (hist first = critical path; others hide under it):
//       [0,nbH):        rank[e]=deg[dst[e]]++   (8 edges/thread, 8 atomic chains)
//       [nbH,nbH+nbC):  efh[e]=fp16(ef[e][:])   (coalesced pre-convert, orig order)
//       [nbH+nbC,...):  t = fp16(node_feat @ W^T)
//   K2a/2b/2c:    offsets = exclusive_scan(deg)  (multi-block; 1-WG scan was 94us, R6)
//   K3 permute:   pos=offsets[dst[e]]+rank[e]; srcs[pos]=src[e]; efs[pos]=efh[e]
//                 plain scatter stores only (NT scatter = 4-5x write amp, R4)
//   K4 aggregate: per node (one wave, lanes=o), 16-deep masked gather chains, fp32 acc,
//                 scalar-path srcs/efs, NT stores for the coalesced write-once out.

#define FEATS 64
#define EDGE_DIM 8

typedef _Float16 half8 __attribute__((ext_vector_type(8)));
typedef float f32x4 __attribute__((ext_vector_type(4)));

// ---- K0: zero deg ----
__global__ void __launch_bounds__(256) zero_kernel(int* __restrict__ p, int n)
{
    int i = blockIdx.x * 256 + threadIdx.x;
    if (i < n) p[i] = 0;
}

// ---- K1: fused hist(8/thread) + ef->fp16 convert + transform ----
__global__ void __launch_bounds__(256) fused_kernel(
    const int* __restrict__ dst, int* __restrict__ deg, int* __restrict__ rank,
    int n_edges, int nbH, int nbC,
    const float* __restrict__ ef, half8* __restrict__ efh,
    const float* __restrict__ nf, const float* __restrict__ W,
    _Float16* __restrict__ t, int n_nodes)
{
    const int tid = threadIdx.x;
    const unsigned bid = blockIdx.x;

    if (bid < (unsigned)nbH) {
        // ---------- histogram: rank[e] = deg[dst[e]]++ , 8 chains in flight ----------
        long i8 = ((long)bid * 256 + tid) * 8;
        if (i8 + 7 < n_edges) {
            int4 d0 = *(const int4*)(dst + i8);
            int4 d1 = *(const int4*)(dst + i8 + 4);
            int4 r0, r1;
            r0.x = atomicAdd(&deg[d0.x], 1);
            r0.y = atomicAdd(&deg[d0.y], 1);
            r0.z = atomicAdd(&deg[d0.z], 1);
            r0.w = atomicAdd(&deg[d0.w], 1);
            r1.x = atomicAdd(&deg[d1.x], 1);
            r1.y = atomicAdd(&deg[d1.y], 1);
            r1.z = atomicAdd(&deg[d1.z], 1);
            r1.w = atomicAdd(&deg[d1.w], 1);
            *(int4*)(rank + i8)     = r0;            // coalesced
            *(int4*)(rank + i8 + 4) = r1;
        } else {
            for (long e = i8; e < n_edges; ++e)
                rank[e] = atomicAdd(&deg[dst[e]], 1);
        }
        return;
    }

    if (bid < (unsigned)(nbH + nbC)) {
        // ---------- convert: efh[e] = fp16(ef[e][:]), fully coalesced ----------
        int e = (bid - nbH) * 256 + tid;
        if (e < n_edges) {
            const f32x4* q = (const f32x4*)(ef + (long)e * EDGE_DIM);
            f32x4 a = q[0], c = q[1];
            half8 h;
            h[0] = (_Float16)a.x; h[1] = (_Float16)a.y;
            h[2] = (_Float16)a.z; h[3] = (_Float16)a.w;
            h[4] = (_Float16)c.x; h[5] = (_Float16)c.y;
            h[6] = (_Float16)c.z; h[7] = (_Float16)c.w;
            efh[e] = h;                              // plain: stays in L2/L3 for permute
        }
        return;
    }

    // ---------- transform: t[n][o] = fp16(sum_i nf[n][i]*W[o][i]) ----------
    __shared__ float sWt[FEATS * 65];
    __shared__ float srow[4][FEATS];
    const int bt = bid - nbH - nbC;

    #pragma unroll
    for (int base = 0; base < FEATS * FEATS; base += 256) {
        int idx = base + tid;
        int o = idx >> 6;
        int i = idx & 63;
        sWt[i * 65 + o] = W[idx];
    }

    const int r = tid >> 6;
    const int o = tid & 63;
    const int node = bt * 4 + r;
    if (node < n_nodes) srow[r][o] = nf[(long)node * FEATS + o];
    __syncthreads();

    if (node >= n_nodes) return;
    float sum = 0.f;
    #pragma unroll
    for (int i = 0; i < FEATS; i++)
        sum += srow[r][i] * sWt[i * 65 + o];
    t[(long)node * FEATS + o] = (_Float16)sum;   // single rounding, fp32 accumulate
}

// ---- K2a: per-block partial sums of deg ----
__global__ void __launch_bounds__(256) partials_kernel(
    const int* __restrict__ deg, int* __restrict__ partials, int n)
{
    __shared__ int s[256];
    int i = blockIdx.x * 256 + threadIdx.x;
    s[threadIdx.x] = (i < n) ? deg[i] : 0;
    __syncthreads();
    for (int off = 128; off > 0; off >>= 1) {
        if (threadIdx.x < off) s[threadIdx.x] += s[threadIdx.x + off];
        __syncthreads();
    }
    if (threadIdx.x == 0) partials[blockIdx.x] = s[0];
}

// ---- K2b: exclusive scan of partials (single block, nb <= 256) ----
__global__ void __launch_bounds__(256) scan_partials_kernel(
    const int* __restrict__ partials, int* __restrict__ pscan, int nb)
{
    __shared__ int s[256];
    int tid = threadIdx.x;
    s[tid] = (tid < nb) ? partials[tid] : 0;
    for (int off = 1; off < 256; off <<= 1) {
        __syncthreads();
        int x = (tid >= off) ? s[tid - off] : 0;
        __syncthreads();
        s[tid] += x;
    }
    __syncthreads();
    pscan[tid] = (tid == 0) ? 0 : s[tid - 1];
}

// ---- K2c: block-local exclusive scan + add partial offset ----
__global__ void __launch_bounds__(256) scan_addback_kernel(
    const int* __restrict__ deg, const int* __restrict__ pscan,
    int* __restrict__ offsets, int n, int n_edges)
{
    __shared__ int s[256];
    int tid = threadIdx.x;
    int i = blockIdx.x * 256 + tid;
    int v = (i < n) ? deg[i] : 0;
    s[tid] = v;
    for (int off = 1; off < 256; off <<= 1) {
        __syncthreads();
        int x = (tid >= off) ? s[tid - off] : 0;
        __syncthreads();
        s[tid] += x;
    }
    __syncthreads();
    if (i < n)
        offsets[i] = pscan[blockIdx.x] + s[tid] - v;   // inclusive - self = exclusive
    if (blockIdx.x == 0 && tid == 0) offsets[n] = n_edges;
}

// ---- K3: atomic-free permute; sequential efh read -> scattered efs write ----
__global__ void __launch_bounds__(256) permute_ef_kernel(
    const int* __restrict__ src, const int* __restrict__ dst,
    const int* __restrict__ rank, const int* __restrict__ offsets,
    const half8* __restrict__ efh,
    int* __restrict__ srcs, half8* __restrict__ efs, int n_edges)
{
    int i4 = (blockIdx.x * 256 + threadIdx.x) * 4;
    if (i4 + 3 < n_edges) {
        int4 s = *(const int4*)(src + i4);
        int4 d = *(const int4*)(dst + i4);
        int4 r = *(const int4*)(rank + i4);
        // 4 independent offsets gathers in flight (L2-resident, 200KB array)
        int p0 = offsets[d.x] + r.x;
        int p1 = offsets[d.y] + r.y;
        int p2 = offsets[d.z] + r.z;
        int p3 = offsets[d.w] + r.w;
        half8 h0 = efh[i4], h1 = efh[i4 + 1], h2 = efh[i4 + 2], h3 = efh[i4 + 3];
        efs[p0] = h0;                            // plain stores: L2 write-combines
        efs[p1] = h1;
        efs[p2] = h2;
        efs[p3] = h3;
        srcs[p0] = s.x; srcs[p1] = s.y; srcs[p2] = s.z; srcs[p3] = s.w;
    } else {
        for (int e = i4; e < n_edges; ++e) {
            int p = offsets[dst[e]] + rank[e];
            srcs[p] = src[e];
            efs[p] = efh[e];
        }
    }
}

// ---- K4: per-node aggregation, 16-deep chains, scalar fp16 ef ----
#define CHUNK 16

__global__ void __launch_bounds__(256) aggregate_seq_kernel(
    const _Float16* __restrict__ t, const half8* __restrict__ efs,
    const int* __restrict__ srcs, const int* __restrict__ offsets,
    const float* __restrict__ b, float* __restrict__ out, int n_nodes)
{
    const int node = __builtin_amdgcn_readfirstlane(
        (int)((blockIdx.x * 256 + threadIdx.x) >> 6));
    const int o = threadIdx.x & 63;
    if (node >= n_nodes) return;

    const int beg = offsets[node];
    const int end = offsets[node + 1];
    float acc[EDGE_DIM];
    #pragma unroll
    for (int k = 0; k < EDGE_DIM; k++) acc[k] = 0.f;

    if (end > beg) {
        const int last = end - 1;      // >= beg >= 0, so clamped idx always valid
        for (int j = beg; j < end; j += CHUNK) {
            int sidx[CHUNK];
            #pragma unroll
            for (int u = 0; u < CHUNK; u++) {
                int jj = j + u;
                sidx[u] = srcs[jj <= last ? jj : last];   // uniform clamp (scalar)
            }
            float tv[CHUNK];
            #pragma unroll
            for (int u = 0; u < CHUNK; u++)               // CHUNK gathers in flight
                tv[u] = (float)t[(long)sidx[u] * FEATS + o];
            #pragma unroll
            for (int u = 0; u < CHUNK; u++) {
                int jj = j + u;
                int ej = jj <= last ? jj : last;
                float tvm = (jj <= last) ? tv[u] : 0.f;   // mask tail
                half8 row = efs[ej];                      // uniform 16B (scalar path)
                #pragma unroll
                for (int k = 0; k < EDGE_DIM; k++)
                    acc[k] += (float)row[k] * tvm;
            }
        }
    }

    const float bo = b[o];
    float* op = out + (long)node * (EDGE_DIM * FEATS) + o;
    // out IS coalesced/full-line: NT is correct here (write-once stream)
    #pragma unroll
    for (int k = 0; k < EDGE_DIM; k++)
        __builtin_nontemporal_store(acc[k] + bo, op + k * FEATS);
}

extern "C" void kernel_launch(void* const* d_in, const int* in_sizes, int n_in,
                              void* d_out, int out_size, void* d_ws, size_t ws_size,
                              hipStream_t stream) {
    const float* node_feat = (const float*)d_in[0];
    const float* edge_feat = (const float*)d_in[1];
    const float* W         = (const float*)d_in[2];
    const float* b         = (const float*)d_in[3];
    const int*   src       = (const int*)d_in[4];
    const int*   dst       = (const int*)d_in[5];
    float* out = (float*)d_out;

    const int n_nodes = in_sizes[0] / FEATS;
    const int n_edges = in_sizes[4];
    const int nb_nodes = (n_nodes + 255) / 256;
    const int nbH = (n_edges + 2047) / 2048;           // hist blocks, 8 edges/thread
    const int nbC = (n_edges + 255) / 256;             // convert blocks, 1 edge/thread
    const int nbT = (n_nodes + 3) / 4;                 // transform blocks
    const int nbP = (n_edges + 1023) / 1024;           // permute blocks, 4 edges/thread

    // workspace layout (4B units)
    int* w = (int*)d_ws;
    _Float16* t   = (_Float16*)w;                      // N*64 halves = N*32 ints
    int* deg      = w + (long)n_nodes * (FEATS / 2);   // N
    int* offsets  = deg + n_nodes;                     // N+1
    int* partials = offsets + n_nodes + 1;             // 256
    int* pscan    = partials + 256;                    // 256
    int* rank     = pscan + 256;                       // E
    int* srcs     = rank + n_edges;                    // E
    uintptr_t ha  = ((uintptr_t)(srcs + n_edges) + 15) & ~(uintptr_t)15;
    half8* efh    = (half8*)ha;                        // E * 16B (orig order)
    half8* efs    = efh + n_edges;                     // E * 16B (dst-sorted)

    zero_kernel<<<nb_nodes, 256, 0, stream>>>(deg, n_nodes);
    fused_kernel<<<nbH + nbC + nbT, 256, 0, stream>>>(
        dst, deg, rank, n_edges, nbH, nbC, edge_feat, efh,
        node_feat, W, t, n_nodes);
    partials_kernel<<<nb_nodes, 256, 0, stream>>>(deg, partials, n_nodes);
    scan_partials_kernel<<<1, 256, 0, stream>>>(partials, pscan, nb_nodes);
    scan_addback_kernel<<<nb_nodes, 256, 0, stream>>>(deg, pscan, offsets,
                                                      n_nodes, n_edges);
    permute_ef_kernel<<<nbP, 256, 0, stream>>>(src, dst, rank, offsets, efh,
                                               srcs, efs, n_edges);

    const long total_ag = (long)n_nodes * 64;
    aggregate_seq_kernel<<<(int)((total_ag + 255) / 256), 256, 0, stream>>>(
        t, efs, srcs, offsets, b, out, n_nodes);
}

// Round 10
// 270.961 us; speedup vs baseline: 1.3332x; 1.0189x over previous
//
#include <hip/hip_runtime.h>

// EfConv forward, CSR-based, fp16 payloads, atomic-free permute, 5 kernels + 1 memset:
//   M0 memset:    deg[:]=0  (hipMemsetAsync; capture-safe, harness uses it itself)
//   K1 fused, 3 block ranges (hist first = critical path; others hide under it):
//       [0,nbH):        rank[e]=deg[dst[e]]++   (8 edges/thread; 800K atomics at
//                       ~12.6G/s = fabric wall, R9-confirmed: MLP doesn't help)
//       [nbH,nbH+nbC):  efh[e]=fp16(ef[e][:])   (coalesced pre-convert, orig order)
//       [nbH+nbC,...):  t = fp16(node_feat @ W^T)
//   K2a partials: per-block sums of deg
//   K2b addback:  each block redundantly scans partials in LDS (<=256 ints, L2-hit)
//                 + block-local scan + write offsets   (merged; was 2 kernels)
//   K3 permute:   pos=offsets[dst[e]]+rank[e]; srcs[pos]=src[e]; efs[pos]=efh[e]
//                 plain scatter stores only (NT scatter = 4-5x write amp, R4)
//   K4 aggregate: per node (one wave, lanes=o), 16-deep masked gather chains, fp32 acc,
//                 scalar-path srcs/efs, NT stores for the coalesced write-once out.

#define FEATS 64
#define EDGE_DIM 8

typedef _Float16 half8 __attribute__((ext_vector_type(8)));
typedef float f32x4 __attribute__((ext_vector_type(4)));

// ---- K1: fused hist(8/thread) + ef->fp16 convert + transform ----
__global__ void __launch_bounds__(256) fused_kernel(
    const int* __restrict__ dst, int* __restrict__ deg, int* __restrict__ rank,
    int n_edges, int nbH, int nbC,
    const float* __restrict__ ef, half8* __restrict__ efh,
    const float* __restrict__ nf, const float* __restrict__ W,
    _Float16* __restrict__ t, int n_nodes)
{
    const int tid = threadIdx.x;
    const unsigned bid = blockIdx.x;

    if (bid < (unsigned)nbH) {
        // ---------- histogram: rank[e] = deg[dst[e]]++ , 8 chains in flight ----------
        long i8 = ((long)bid * 256 + tid) * 8;
        if (i8 + 7 < n_edges) {
            int4 d0 = *(const int4*)(dst + i8);
            int4 d1 = *(const int4*)(dst + i8 + 4);
            int4 r0, r1;
            r0.x = atomicAdd(&deg[d0.x], 1);
            r0.y = atomicAdd(&deg[d0.y], 1);
            r0.z = atomicAdd(&deg[d0.z], 1);
            r0.w = atomicAdd(&deg[d0.w], 1);
            r1.x = atomicAdd(&deg[d1.x], 1);
            r1.y = atomicAdd(&deg[d1.y], 1);
            r1.z = atomicAdd(&deg[d1.z], 1);
            r1.w = atomicAdd(&deg[d1.w], 1);
            *(int4*)(rank + i8)     = r0;            // coalesced
            *(int4*)(rank + i8 + 4) = r1;
        } else {
            for (long e = i8; e < n_edges; ++e)
                rank[e] = atomicAdd(&deg[dst[e]], 1);
        }
        return;
    }

    if (bid < (unsigned)(nbH + nbC)) {
        // ---------- convert: efh[e] = fp16(ef[e][:]), fully coalesced ----------
        int e = (bid - nbH) * 256 + tid;
        if (e < n_edges) {
            const f32x4* q = (const f32x4*)(ef + (long)e * EDGE_DIM);
            f32x4 a = q[0], c = q[1];
            half8 h;
            h[0] = (_Float16)a.x; h[1] = (_Float16)a.y;
            h[2] = (_Float16)a.z; h[3] = (_Float16)a.w;
            h[4] = (_Float16)c.x; h[5] = (_Float16)c.y;
            h[6] = (_Float16)c.z; h[7] = (_Float16)c.w;
            efh[e] = h;                              // plain: stays in L2/L3 for permute
        }
        return;
    }

    // ---------- transform: t[n][o] = fp16(sum_i nf[n][i]*W[o][i]) ----------
    __shared__ float sWt[FEATS * 65];
    __shared__ float srow[4][FEATS];
    const int bt = bid - nbH - nbC;

    #pragma unroll
    for (int base = 0; base < FEATS * FEATS; base += 256) {
        int idx = base + tid;
        int o = idx >> 6;
        int i = idx & 63;
        sWt[i * 65 + o] = W[idx];
    }

    const int r = tid >> 6;
    const int o = tid & 63;
    const int node = bt * 4 + r;
    if (node < n_nodes) srow[r][o] = nf[(long)node * FEATS + o];
    __syncthreads();

    if (node >= n_nodes) return;
    float sum = 0.f;
    #pragma unroll
    for (int i = 0; i < FEATS; i++)
        sum += srow[r][i] * sWt[i * 65 + o];
    t[(long)node * FEATS + o] = (_Float16)sum;   // single rounding, fp32 accumulate
}

// ---- K2a: per-block partial sums of deg ----
__global__ void __launch_bounds__(256) partials_kernel(
    const int* __restrict__ deg, int* __restrict__ partials, int n)
{
    __shared__ int s[256];
    int i = blockIdx.x * 256 + threadIdx.x;
    s[threadIdx.x] = (i < n) ? deg[i] : 0;
    __syncthreads();
    for (int off = 128; off > 0; off >>= 1) {
        if (threadIdx.x < off) s[threadIdx.x] += s[threadIdx.x + off];
        __syncthreads();
    }
    if (threadIdx.x == 0) partials[blockIdx.x] = s[0];
}

// ---- K2b: merged partials-scan (redundant per block) + local scan + addback ----
__global__ void __launch_bounds__(256) scan_addback_kernel(
    const int* __restrict__ deg, const int* __restrict__ partials,
    int* __restrict__ offsets, int nb, int n, int n_edges)
{
    __shared__ int sp[256];
    __shared__ int s[256];
    const int tid = threadIdx.x;

    // 1) every block scans the (<=256) per-block partials in LDS (inclusive)
    sp[tid] = (tid < nb) ? partials[tid] : 0;
    for (int off = 1; off < 256; off <<= 1) {
        __syncthreads();
        int x = (tid >= off) ? sp[tid - off] : 0;
        __syncthreads();
        sp[tid] += x;
    }

    // 2) block-local inclusive scan of deg
    int i = blockIdx.x * 256 + tid;
    int v = (i < n) ? deg[i] : 0;
    s[tid] = v;
    for (int off = 1; off < 256; off <<= 1) {
        __syncthreads();
        int x = (tid >= off) ? s[tid - off] : 0;
        __syncthreads();
        s[tid] += x;
    }
    __syncthreads();

    // 3) exclusive global offset = block-prefix + (inclusive - self)
    if (i < n) {
        int pbase = (blockIdx.x == 0) ? 0 : sp[blockIdx.x - 1];
        offsets[i] = pbase + s[tid] - v;
    }
    if (blockIdx.x == 0 && tid == 0) offsets[n] = n_edges;
}

// ---- K3: atomic-free permute; sequential efh read -> scattered efs write ----
__global__ void __launch_bounds__(256) permute_ef_kernel(
    const int* __restrict__ src, const int* __restrict__ dst,
    const int* __restrict__ rank, const int* __restrict__ offsets,
    const half8* __restrict__ efh,
    int* __restrict__ srcs, half8* __restrict__ efs, int n_edges)
{
    int i4 = (blockIdx.x * 256 + threadIdx.x) * 4;
    if (i4 + 3 < n_edges) {
        int4 s = *(const int4*)(src + i4);
        int4 d = *(const int4*)(dst + i4);
        int4 r = *(const int4*)(rank + i4);
        // 4 independent offsets gathers in flight (L2-resident, 200KB array)
        int p0 = offsets[d.x] + r.x;
        int p1 = offsets[d.y] + r.y;
        int p2 = offsets[d.z] + r.z;
        int p3 = offsets[d.w] + r.w;
        half8 h0 = efh[i4], h1 = efh[i4 + 1], h2 = efh[i4 + 2], h3 = efh[i4 + 3];
        efs[p0] = h0;                            // plain stores: L2 write-combines
        efs[p1] = h1;
        efs[p2] = h2;
        efs[p3] = h3;
        srcs[p0] = s.x; srcs[p1] = s.y; srcs[p2] = s.z; srcs[p3] = s.w;
    } else {
        for (int e = i4; e < n_edges; ++e) {
            int p = offsets[dst[e]] + rank[e];
            srcs[p] = src[e];
            efs[p] = efh[e];
        }
    }
}

// ---- K4: per-node aggregation, 16-deep chains, scalar fp16 ef ----
#define CHUNK 16

__global__ void __launch_bounds__(256) aggregate_seq_kernel(
    const _Float16* __restrict__ t, const half8* __restrict__ efs,
    const int* __restrict__ srcs, const int* __restrict__ offsets,
    const float* __restrict__ b, float* __restrict__ out, int n_nodes)
{
    const int node = __builtin_amdgcn_readfirstlane(
        (int)((blockIdx.x * 256 + threadIdx.x) >> 6));
    const int o = threadIdx.x & 63;
    if (node >= n_nodes) return;

    const int beg = offsets[node];
    const int end = offsets[node + 1];
    float acc[EDGE_DIM];
    #pragma unroll
    for (int k = 0; k < EDGE_DIM; k++) acc[k] = 0.f;

    if (end > beg) {
        const int last = end - 1;      // >= beg >= 0, so clamped idx always valid
        for (int j = beg; j < end; j += CHUNK) {
            int sidx[CHUNK];
            #pragma unroll
            for (int u = 0; u < CHUNK; u++) {
                int jj = j + u;
                sidx[u] = srcs[jj <= last ? jj : last];   // uniform clamp (scalar)
            }
            float tv[CHUNK];
            #pragma unroll
            for (int u = 0; u < CHUNK; u++)               // CHUNK gathers in flight
                tv[u] = (float)t[(long)sidx[u] * FEATS + o];
            #pragma unroll
            for (int u = 0; u < CHUNK; u++) {
                int jj = j + u;
                int ej = jj <= last ? jj : last;
                float tvm = (jj <= last) ? tv[u] : 0.f;   // mask tail
                half8 row = efs[ej];                      // uniform 16B (scalar path)
                #pragma unroll
                for (int k = 0; k < EDGE_DIM; k++)
                    acc[k] += (float)row[k] * tvm;
            }
        }
    }

    const float bo = b[o];
    float* op = out + (long)node * (EDGE_DIM * FEATS) + o;
    // out IS coalesced/full-line: NT is correct here (write-once stream)
    #pragma unroll
    for (int k = 0; k < EDGE_DIM; k++)
        __builtin_nontemporal_store(acc[k] + bo, op + k * FEATS);
}

extern "C" void kernel_launch(void* const* d_in, const int* in_sizes, int n_in,
                              void* d_out, int out_size, void* d_ws, size_t ws_size,
                              hipStream_t stream) {
    const float* node_feat = (const float*)d_in[0];
    const float* edge_feat = (const float*)d_in[1];
    const float* W         = (const float*)d_in[2];
    const float* b         = (const float*)d_in[3];
    const int*   src       = (const int*)d_in[4];
    const int*   dst       = (const int*)d_in[5];
    float* out = (float*)d_out;

    const int n_nodes = in_sizes[0] / FEATS;
    const int n_edges = in_sizes[4];
    const int nb_nodes = (n_nodes + 255) / 256;        // <= 256 required by scan
    const int nbH = (n_edges + 2047) / 2048;           // hist blocks, 8 edges/thread
    const int nbC = (n_edges + 255) / 256;             // convert blocks, 1 edge/thread
    const int nbT = (n_nodes + 3) / 4;                 // transform blocks
    const int nbP = (n_edges + 1023) / 1024;           // permute blocks, 4 edges/thread

    // workspace layout (4B units)
    int* w = (int*)d_ws;
    _Float16* t   = (_Float16*)w;                      // N*64 halves = N*32 ints
    int* deg      = w + (long)n_nodes * (FEATS / 2);   // N
    int* offsets  = deg + n_nodes;                     // N+1
    int* partials = offsets + n_nodes + 1;             // 256
    int* rank     = partials + 256;                    // E
    int* srcs     = rank + n_edges;                    // E
    uintptr_t ha  = ((uintptr_t)(srcs + n_edges) + 15) & ~(uintptr_t)15;
    half8* efh    = (half8*)ha;                        // E * 16B (orig order)
    half8* efs    = efh + n_edges;                     // E * 16B (dst-sorted)

    hipMemsetAsync(deg, 0, (size_t)n_nodes * 4, stream);
    fused_kernel<<<nbH + nbC + nbT, 256, 0, stream>>>(
        dst, deg, rank, n_edges, nbH, nbC, edge_feat, efh,
        node_feat, W, t, n_nodes);
    partials_kernel<<<nb_nodes, 256, 0, stream>>>(deg, partials, n_nodes);
    scan_addback_kernel<<<nb_nodes, 256, 0, stream>>>(deg, partials, offsets,
                                                      nb_nodes, n_nodes, n_edges);
    permute_ef_kernel<<<nbP, 256, 0, stream>>>(src, dst, rank, offsets, efh,
                                               srcs, efs, n_edges);

    const long total_ag = (long)n_nodes * 64;
    aggregate_seq_kernel<<<(int)((total_ag + 255) / 256), 256, 0, stream>>>(
        t, efs, srcs, offsets, b, out, n_nodes);
}